// Round 1
// 452.918 us; speedup vs baseline: 1.0609x; 1.0609x over previous
//
#include <hip/hip_runtime.h>
#include <math.h>

#define MEM 32768
#define UNITS 128
#define BATCH 256
#define IN_DIM 512
#define ZDIM 512      // 4*UNITS
#define CI_DIM 768    // IN_DIM + UNITS(r) + UNITS(h)

// ---- d_out offsets (floats), reference return order ----
#define OFF_READ   0
#define OFF_MEMORY (OFF_READ + BATCH*UNITS)        // 32768
#define OFF_CWU    (OFF_MEMORY + MEM*UNITS)        // 4227072
#define OFF_CWLU   (OFF_CWU + MEM*BATCH)           // 12615680
#define OFF_CWR    (OFF_CWLU + MEM*BATCH)          // 21004288
#define OFF_CWW    (OFF_CWR + MEM*BATCH)           // 29392896
#define OFF_H      (OFF_CWW + MEM*BATCH)           // 37781504
#define OFF_C      (OFF_H + BATCH*UNITS)           // 37814272

// ---- ws offsets (bytes) ----
#define WS_HT     0                                // float[UNITS*BATCH] (scaled h^T)
#define WS_COLMIN (UNITS*BATCH*4)                  // u64[BATCH]
#define WS_MINV   (WS_COLMIN + BATCH*8)            // float[BATCH]
#define WS_COUNT  (WS_MINV + BATCH*4)              // int[MEM]
#define WS_BHI    (WS_COUNT + MEM*4)               // short8[16*256] swizzled B hi (64 KB)
#define WS_BLO    (WS_BHI + 65536)                 // short8[16*256] swizzled B lo (64 KB)
#define WS_PART   (512*1024)                       // float[64][BATCH][UNITS] split-K partials
#define PART_BYTES (64*BATCH*UNITS*4)              // 8 MB

typedef __attribute__((ext_vector_type(8))) short short8;
typedef __attribute__((ext_vector_type(4))) float f32x4;

__device__ __forceinline__ float sigf(float x) { return 1.0f / (1.0f + __expf(-x)); }
// bf16 round-to-nearest-even from f32 (bits as short)
__device__ __forceinline__ short bf16r(float x) {
    unsigned u = __float_as_uint(x);
    return (short)((u + 0x7fffu + ((u >> 16) & 1u)) >> 16);
}
__device__ __forceinline__ float bf16f(short h) {
    return __uint_as_float(((unsigned)(unsigned short)h) << 16);
}

// ------------------------------------------------------------------
// K1: LSTM cell (4 rows/block), h/c outputs, h-norm, scaled h^T to ws
// ------------------------------------------------------------------
__global__ __launch_bounds__(512) void k_lstm(
    const float* __restrict__ inp, const float* __restrict__ r_tm1,
    const float* __restrict__ h_tm1, const float* __restrict__ c_tm1,
    const float* __restrict__ W, const float* __restrict__ RW,
    const float* __restrict__ bias,
    float* __restrict__ out, float* __restrict__ hT)
{
    __shared__ float ci[4][CI_DIM];
    __shared__ float zl[4][ZDIM];
    __shared__ float part[8];
    const int t = threadIdx.x;
    const int row0 = blockIdx.x * 4;

    for (int i = t; i < 4 * CI_DIM; i += 512) {
        int r = i / CI_DIM, j = i - r * CI_DIM;
        int row = row0 + r;
        float v;
        if (j < IN_DIM)              v = inp[row * IN_DIM + j];
        else if (j < IN_DIM + UNITS) v = r_tm1[row * UNITS + (j - IN_DIM)];
        else                         v = h_tm1[row * UNITS + (j - IN_DIM - UNITS)];
        ci[r][j] = v;
    }
    __syncthreads();

    float b = bias[t];
    float z0 = b, z1 = b, z2 = b, z3 = b;
    for (int k4 = 0; k4 < (IN_DIM + UNITS) / 4; ++k4) {
        float w0 = W[(k4 * 4 + 0) * ZDIM + t];
        float w1 = W[(k4 * 4 + 1) * ZDIM + t];
        float w2 = W[(k4 * 4 + 2) * ZDIM + t];
        float w3 = W[(k4 * 4 + 3) * ZDIM + t];
        float4 a0 = *(const float4*)&ci[0][k4 * 4];
        float4 a1 = *(const float4*)&ci[1][k4 * 4];
        float4 a2 = *(const float4*)&ci[2][k4 * 4];
        float4 a3 = *(const float4*)&ci[3][k4 * 4];
        z0 += a0.x * w0 + a0.y * w1 + a0.z * w2 + a0.w * w3;
        z1 += a1.x * w0 + a1.y * w1 + a1.z * w2 + a1.w * w3;
        z2 += a2.x * w0 + a2.y * w1 + a2.z * w2 + a2.w * w3;
        z3 += a3.x * w0 + a3.y * w1 + a3.z * w2 + a3.w * w3;
    }
    for (int k4 = 0; k4 < UNITS / 4; ++k4) {
        float w0 = RW[(k4 * 4 + 0) * ZDIM + t];
        float w1 = RW[(k4 * 4 + 1) * ZDIM + t];
        float w2 = RW[(k4 * 4 + 2) * ZDIM + t];
        float w3 = RW[(k4 * 4 + 3) * ZDIM + t];
        const int base = IN_DIM + UNITS + k4 * 4;
        float4 a0 = *(const float4*)&ci[0][base];
        float4 a1 = *(const float4*)&ci[1][base];
        float4 a2 = *(const float4*)&ci[2][base];
        float4 a3 = *(const float4*)&ci[3][base];
        z0 += a0.x * w0 + a0.y * w1 + a0.z * w2 + a0.w * w3;
        z1 += a1.x * w0 + a1.y * w1 + a1.z * w2 + a1.w * w3;
        z2 += a2.x * w0 + a2.y * w1 + a2.z * w2 + a2.w * w3;
        z3 += a3.x * w0 + a3.y * w1 + a3.z * w2 + a3.w * w3;
    }
    zl[0][t] = z0; zl[1][t] = z1; zl[2][t] = z2; zl[3][t] = z3;
    __syncthreads();

    const int r = t >> 7, u = t & 127;
    const int row = row0 + r;
    float iv = zl[r][u], fv = zl[r][UNITS + u], gv = zl[r][2 * UNITS + u], ov = zl[r][3 * UNITS + u];
    float ig = sigf(iv), fg = sigf(fv), og = sigf(ov);
    float gt = tanhf(gv);
    float cn = fg * c_tm1[row * UNITS + u] + ig * gt;
    float hn = og * tanhf(cn);
    out[OFF_C + row * UNITS + u] = cn;
    out[OFF_H + row * UNITS + u] = hn;

    float s = hn * hn;
    for (int d = 1; d < 64; d <<= 1) s += __shfl_xor(s, d, 64);
    int wave = t >> 6;
    if ((t & 63) == 0) part[wave] = s;
    __syncthreads();
    float inv = rsqrtf(fmaxf(part[2 * r] + part[2 * r + 1], 1e-12f));
    hT[u * BATCH + row] = hn * inv;
}

// ------------------------------------------------------------------
// K2a: normalize m rows + write A operand (bf16 hi/lo) in MFMA-A swizzle.
// ------------------------------------------------------------------
__global__ __launch_bounds__(256) void k_prep_m(
    const float* __restrict__ m, short8* __restrict__ Ahi, short8* __restrict__ Alo)
{
    __shared__ float part[16 * 17];
    const int t = threadIdx.x, mt = blockIdx.x;
    const int s = t >> 6, L = t & 63;
    const int row = mt * 16 + (L & 15);
    const int k0 = s * 32 + (L >> 4) * 8;
    float x[8];
    float4 v0 = *(const float4*)&m[row * UNITS + k0];
    float4 v1 = *(const float4*)&m[row * UNITS + k0 + 4];
    x[0] = v0.x; x[1] = v0.y; x[2] = v0.z; x[3] = v0.w;
    x[4] = v1.x; x[5] = v1.y; x[6] = v1.z; x[7] = v1.w;
    float ss = 0.f;
#pragma unroll
    for (int j = 0; j < 8; ++j) ss += x[j] * x[j];
    part[(L & 15) * 17 + s * 4 + (L >> 4)] = ss;
    __syncthreads();
    float tot = 0.f;
#pragma unroll
    for (int i = 0; i < 16; ++i) tot += part[(L & 15) * 17 + i];
    float inv = rsqrtf(fmaxf(tot, 1e-12f));
    short8 hi, lo;
#pragma unroll
    for (int j = 0; j < 8; ++j) {
        float xv = x[j] * inv;
        short hb = bf16r(xv);
        hi[j] = hb;
        lo[j] = bf16r(xv - bf16f(hb));
    }
    Ahi[mt * 256 + t] = hi;
    Alo[mt * 256 + t] = lo;
}

// ------------------------------------------------------------------
// K2b: swizzle normalized h^T into MFMA-B layout (bf16 hi/lo), and
// (blocks 0..7) swizzle raw h into K-major MFMA-B fragments for k_memory.
// Raw-h frag layout: B2[(kt*8 + nt)*64 + (u&15) + 16*((b&31)>>3)][j=b&7],
// kt = b>>5, nt = u>>4.
// ------------------------------------------------------------------
__global__ __launch_bounds__(256) void k_hswz(
    const float* __restrict__ hT, short8* __restrict__ Bhi, short8* __restrict__ Blo,
    const float* __restrict__ h, short8* __restrict__ B2h, short8* __restrict__ B2l)
{
    const int t = threadIdx.x, bt = blockIdx.x;
    const int s = t >> 6, L = t & 63;
    const int b = bt * 16 + (L & 15);
    const int k0 = s * 32 + (L >> 4) * 8;
    short8 hi, lo;
#pragma unroll
    for (int j = 0; j < 8; ++j) {
        float x = hT[(k0 + j) * BATCH + b];
        short hb = bf16r(x);
        hi[j] = hb;
        lo[j] = bf16r(x - bf16f(hb));
    }
    Bhi[bt * 256 + t] = hi;
    Blo[bt * 256 + t] = lo;

    if (bt < 8) {  // raw-h fragments (K = batch), block bt covers b-rows bt*32..+31
        const int u = t & 127, op = t >> 7;
#pragma unroll
        for (int oo = 0; oo < 2; ++oo) {
            const int oct = op + 2 * oo;
            short8 h2, l2;
#pragma unroll
            for (int j = 0; j < 8; ++j) {
                float x = h[(bt * 32 + oct * 8 + j) * UNITS + u];
                short hb = bf16r(x);
                h2[j] = hb;
                l2[j] = bf16r(x - bf16f(hb));
            }
            B2h[(bt * 8 + (u >> 4)) * 64 + (u & 15) + 16 * oct] = h2;
            B2l[(bt * 8 + (u >> 4)) * 64 + (u & 15) + 16 * oct] = l2;
        }
    }
}

// ------------------------------------------------------------------
// K3 v2: cos (MFMA bf16 hi/lo split) + softmax + c_wr/c_ww/c_wu + col-min.
// ------------------------------------------------------------------
__global__ __launch_bounds__(256) void k_cos_softmax(
    const short8* __restrict__ Ahi, const short8* __restrict__ Alo,
    const short8* __restrict__ Bhi, const short8* __restrict__ Blo,
    const float* __restrict__ cwr_tm1, const float* __restrict__ cwlu_tm1,
    const float* __restrict__ cwu_tm1, const float* __restrict__ wgp,
    float* __restrict__ out, unsigned long long* __restrict__ colmin)
{
    __shared__ float cosLS[32 * 260];          // 33280 B; reused for wave minima
    const int t = threadIdx.x;
    const int w = t >> 6, L = t & 63;
    const int m0 = blockIdx.x * 32;
    const int mt = blockIdx.x * 2 + (w >> 1);
    const int bh = w & 1;

    short8 ah[4], al[4];
#pragma unroll
    for (int s = 0; s < 4; ++s) {
        ah[s] = Ahi[(mt * 4 + s) * 64 + L];
        al[s] = Alo[(mt * 4 + s) * 64 + L];
    }

    const int rbase = (w >> 1) * 16 + (L >> 4) * 4;
#pragma unroll
    for (int i = 0; i < 8; ++i) {
        const int bt = bh * 8 + i;
        f32x4 acc = {0.f, 0.f, 0.f, 0.f};
#pragma unroll
        for (int s = 0; s < 4; ++s) {
            short8 bhv = Bhi[(bt * 4 + s) * 64 + L];
            short8 blv = Blo[(bt * 4 + s) * 64 + L];
            acc = __builtin_amdgcn_mfma_f32_16x16x32_bf16(ah[s], bhv, acc, 0, 0, 0);
            acc = __builtin_amdgcn_mfma_f32_16x16x32_bf16(ah[s], blv, acc, 0, 0, 0);
            acc = __builtin_amdgcn_mfma_f32_16x16x32_bf16(al[s], bhv, acc, 0, 0, 0);
        }
        const int col = bt * 16 + (L & 15);
#pragma unroll
        for (int r = 0; r < 4; ++r) cosLS[(rbase + r) * 260 + col] = acc[r];
    }
    __syncthreads();

    // ---- phase 2: per-row softmax + ew outputs; wave w owns rows w*8..w*8+7
    const float wg = sigf(wgp[0]);
    const float wgc = 1.0f - wg;
    unsigned long long mk0 = ~0ULL, mk1 = ~0ULL, mk2 = ~0ULL, mk3 = ~0ULL;

#pragma unroll
    for (int i = 0; i < 8; ++i) {
        int ml = w * 8 + i;
        int row = m0 + ml;
        float4 v = *(const float4*)&cosLS[ml * 260 + L * 4];
        float mx = fmaxf(fmaxf(v.x, v.y), fmaxf(v.z, v.w));
        for (int d = 1; d < 64; d <<= 1) mx = fmaxf(mx, __shfl_xor(mx, d, 64));
        float4 e;
        e.x = __expf(v.x - mx); e.y = __expf(v.y - mx);
        e.z = __expf(v.z - mx); e.w = __expf(v.w - mx);
        float s = e.x + e.y + e.z + e.w;
        for (int d = 1; d < 64; d <<= 1) s += __shfl_xor(s, d, 64);
        float is = 1.0f / s;
        float4 wr; wr.x = e.x * is; wr.y = e.y * is; wr.z = e.z * is; wr.w = e.w * is;
        *(float4*)&out[OFF_CWR + row * BATCH + L * 4] = wr;

        float4 pr = *(const float4*)&cwr_tm1[row * BATCH + L * 4];
        float4 pl = *(const float4*)&cwlu_tm1[row * BATCH + L * 4];
        float4 ww;
        ww.x = wg * pr.x + wgc + pl.x; ww.y = wg * pr.y + wgc + pl.y;
        ww.z = wg * pr.z + wgc + pl.z; ww.w = wg * pr.w + wgc + pl.w;
        *(float4*)&out[OFF_CWW + row * BATCH + L * 4] = ww;

        float4 pu = *(const float4*)&cwu_tm1[row * BATCH + L * 4];
        float4 wu;
        wu.x = 0.95f * pu.x + wr.x + ww.x; wu.y = 0.95f * pu.y + wr.y + ww.y;
        wu.z = 0.95f * pu.z + wr.z + ww.z; wu.w = 0.95f * pu.w + wr.w + ww.w;
        *(float4*)&out[OFF_CWU + row * BATCH + L * 4] = wu;

        unsigned idxc = (unsigned)(MEM - 1 - row);
        unsigned long long k;
        k = ((unsigned long long)__float_as_uint(wu.x) << 32) | idxc; if (k < mk0) mk0 = k;
        k = ((unsigned long long)__float_as_uint(wu.y) << 32) | idxc; if (k < mk1) mk1 = k;
        k = ((unsigned long long)__float_as_uint(wu.z) << 32) | idxc; if (k < mk2) mk2 = k;
        k = ((unsigned long long)__float_as_uint(wu.w) << 32) | idxc; if (k < mk3) mk3 = k;
    }
    __syncthreads();
    unsigned long long* wmin = (unsigned long long*)cosLS;
    wmin[w * BATCH + L * 4 + 0] = mk0;
    wmin[w * BATCH + L * 4 + 1] = mk1;
    wmin[w * BATCH + L * 4 + 2] = mk2;
    wmin[w * BATCH + L * 4 + 3] = mk3;
    __syncthreads();
    {
        unsigned long long a = wmin[t];
        unsigned long long b2 = wmin[BATCH + t];
        unsigned long long c2 = wmin[2 * BATCH + t];
        unsigned long long d2 = wmin[3 * BATCH + t];
        unsigned long long k = a < b2 ? a : b2;
        if (c2 < k) k = c2;
        if (d2 < k) k = d2;
        if (k < colmin[t]) atomicMin(&colmin[t], k);
    }
}

// ------------------------------------------------------------------
// K4: decode column minima -> minv + argmin counts
// ------------------------------------------------------------------
__global__ void k_decode(const unsigned long long* __restrict__ colmin,
                         float* __restrict__ minv, int* __restrict__ count)
{
    int t = threadIdx.x;
    unsigned long long k = colmin[t];
    minv[t] = __uint_as_float((unsigned)(k >> 32));
    int idx = MEM - 1 - (int)(unsigned)(k & 0xffffffffu);
    atomicAdd(&count[idx], 1);
}

// ------------------------------------------------------------------
// K5: c_wlu = (c_wu <= minv[b])
// ------------------------------------------------------------------
__global__ __launch_bounds__(256) void k_wlu(const float* __restrict__ cwu,
                                             const float* __restrict__ minv,
                                             float* __restrict__ wlu)
{
    int i = blockIdx.x * 256 + threadIdx.x;   // float4 index
    float4 v = *(const float4*)&cwu[i * 4];
    float4 mv = *(const float4*)&minv[(i & 63) * 4];
    float4 r;
    r.x = (v.x <= mv.x) ? 1.0f : 0.0f;
    r.y = (v.y <= mv.y) ? 1.0f : 0.0f;
    r.z = (v.z <= mv.z) ? 1.0f : 0.0f;
    r.w = (v.w <= mv.w) ? 1.0f : 0.0f;
    *(float4*)&wlu[i * 4] = r;
}

// ------------------------------------------------------------------
// K6 v3: memory = c_ww @ h + (BATCH - count)*m, MFMA bf16 hi/lo split.
// Grid 256 blocks x 128 m-rows. N = 128 u, K = 256 b (8 K-steps of 32).
// 4 waves; wave w owns mt {2w, 2w+1}, all 8 nt. B from precomputed B2 frags.
// ------------------------------------------------------------------
__global__ __launch_bounds__(256) void k_memory(
    const float* __restrict__ cww, const short8* __restrict__ B2h,
    const short8* __restrict__ B2l, const float* __restrict__ m,
    const int* __restrict__ count, float* __restrict__ mem_out)
{
    __shared__ short8 Ah[8 * 64], Al[8 * 64];
    const int t = threadIdx.x;
    const int w = t >> 6, L = t & 63;
    const int m0 = blockIdx.x * 128;
    const int mr = t & 127;          // m-row within block (A staging role)
    const int op = t >> 7;           // octet pair selector

    f32x4 zero = {0.f, 0.f, 0.f, 0.f};
    f32x4 acc[2][8];
#pragma unroll
    for (int mi = 0; mi < 2; ++mi)
#pragma unroll
        for (int nt = 0; nt < 8; ++nt) acc[mi][nt] = zero;

    // prefetch A tile for ks=0: cww[m0+mr][oct*8 .. +8]
    float ax[2][8];
#pragma unroll
    for (int oo = 0; oo < 2; ++oo) {
        const float* src = &cww[(size_t)(m0 + mr) * BATCH + (op + 2 * oo) * 8];
        float4 v0 = *(const float4*)src;
        float4 v1 = *(const float4*)(src + 4);
        ax[oo][0] = v0.x; ax[oo][1] = v0.y; ax[oo][2] = v0.z; ax[oo][3] = v0.w;
        ax[oo][4] = v1.x; ax[oo][5] = v1.y; ax[oo][6] = v1.z; ax[oo][7] = v1.w;
    }

    for (int ks = 0; ks < 8; ++ks) {
        // convert & store A fragments
#pragma unroll
        for (int oo = 0; oo < 2; ++oo) {
            const int oct = op + 2 * oo;
            short8 hi, lo;
#pragma unroll
            for (int j = 0; j < 8; ++j) {
                short hb = bf16r(ax[oo][j]);
                hi[j] = hb;
                lo[j] = bf16r(ax[oo][j] - bf16f(hb));
            }
            Ah[(mr >> 4) * 64 + (mr & 15) + 16 * oct] = hi;
            Al[(mr >> 4) * 64 + (mr & 15) + 16 * oct] = lo;
        }
        __syncthreads();
        if (ks < 7) {   // prefetch next A tile under the MFMA phase
#pragma unroll
            for (int oo = 0; oo < 2; ++oo) {
                const float* src = &cww[(size_t)(m0 + mr) * BATCH + (ks + 1) * 32 + (op + 2 * oo) * 8];
                float4 v0 = *(const float4*)src;
                float4 v1 = *(const float4*)(src + 4);
                ax[oo][0] = v0.x; ax[oo][1] = v0.y; ax[oo][2] = v0.z; ax[oo][3] = v0.w;
                ax[oo][4] = v1.x; ax[oo][5] = v1.y; ax[oo][6] = v1.z; ax[oo][7] = v1.w;
            }
        }
        short8 a_h0 = Ah[(2 * w) * 64 + L],     a_l0 = Al[(2 * w) * 64 + L];
        short8 a_h1 = Ah[(2 * w + 1) * 64 + L], a_l1 = Al[(2 * w + 1) * 64 + L];
#pragma unroll
        for (int nt = 0; nt < 8; ++nt) {
            short8 b_h = B2h[(ks * 8 + nt) * 64 + L];
            short8 b_l = B2l[(ks * 8 + nt) * 64 + L];
            acc[0][nt] = __builtin_amdgcn_mfma_f32_16x16x32_bf16(a_h0, b_h, acc[0][nt], 0, 0, 0);
            acc[0][nt] = __builtin_amdgcn_mfma_f32_16x16x32_bf16(a_h0, b_l, acc[0][nt], 0, 0, 0);
            acc[0][nt] = __builtin_amdgcn_mfma_f32_16x16x32_bf16(a_l0, b_h, acc[0][nt], 0, 0, 0);
            acc[1][nt] = __builtin_amdgcn_mfma_f32_16x16x32_bf16(a_h1, b_h, acc[1][nt], 0, 0, 0);
            acc[1][nt] = __builtin_amdgcn_mfma_f32_16x16x32_bf16(a_h1, b_l, acc[1][nt], 0, 0, 0);
            acc[1][nt] = __builtin_amdgcn_mfma_f32_16x16x32_bf16(a_l1, b_h, acc[1][nt], 0, 0, 0);
        }
        __syncthreads();
    }

    // epilogue: C row = mt*16 + (L>>4)*4 + r, col = nt*16 + (L&15)
#pragma unroll
    for (int mi = 0; mi < 2; ++mi) {
#pragma unroll
        for (int r = 0; r < 4; ++r) {
            const int row = m0 + (2 * w + mi) * 16 + (L >> 4) * 4 + r;
            const float sc = (float)(BATCH - count[row]);
#pragma unroll
            for (int nt = 0; nt < 8; ++nt) {
                const int u = nt * 16 + (L & 15);
                mem_out[row * UNITS + u] = acc[mi][nt][r] + sc * m[row * UNITS + u];
            }
        }
    }
}

// ------------------------------------------------------------------
// K7 v3: read = c_wr^T @ m via MFMA bf16 hi/lo split, split-K.
// Grid 256 = 64 k-chunks x 4 batch-quarters. Block: M=64 b, N=128 u, K=512 m.
// 16 K-steps of 32; coalesced column-octet staging + next-tile prefetch.
// ------------------------------------------------------------------
__global__ __launch_bounds__(256) void k_read(
    const float* __restrict__ cwr, const float* __restrict__ m,
    float* __restrict__ dst, int use_part)
{
    __shared__ short8 Ah[4 * 64], Al[4 * 64];
    __shared__ short8 Bh[8 * 64], Bl[8 * 64];
    const int t = threadIdx.x;
    const int w = t >> 6, L = t & 63;
    const int kc = blockIdx.x >> 2;
    const int bq = blockIdx.x & 3;
    const int k0 = kc * 512;

    const int ab = t & 63;           // b within quarter (A staging role)
    const int aoct = t >> 6;         // 0..3
    const int bu = t & 127;          // u (B staging role)
    const int bop = t >> 7;          // 0..1

    f32x4 zero = {0.f, 0.f, 0.f, 0.f};
    f32x4 acc[8];
#pragma unroll
    for (int i = 0; i < 8; ++i) acc[i] = zero;

    float axr[8];
    float bxr[2][8];
#pragma unroll
    for (int j = 0; j < 8; ++j)
        axr[j] = cwr[(size_t)(k0 + aoct * 8 + j) * BATCH + bq * 64 + ab];
#pragma unroll
    for (int oo = 0; oo < 2; ++oo)
#pragma unroll
        for (int j = 0; j < 8; ++j)
            bxr[oo][j] = m[(size_t)(k0 + (bop + 2 * oo) * 8 + j) * UNITS + bu];

    for (int ks = 0; ks < 16; ++ks) {
        {   // convert & store fragments
            short8 hi, lo;
#pragma unroll
            for (int j = 0; j < 8; ++j) {
                short hb = bf16r(axr[j]);
                hi[j] = hb;
                lo[j] = bf16r(axr[j] - bf16f(hb));
            }
            Ah[(ab >> 4) * 64 + (ab & 15) + 16 * aoct] = hi;
            Al[(ab >> 4) * 64 + (ab & 15) + 16 * aoct] = lo;
#pragma unroll
            for (int oo = 0; oo < 2; ++oo) {
                short8 h2, l2;
#pragma unroll
                for (int j = 0; j < 8; ++j) {
                    short hb = bf16r(bxr[oo][j]);
                    h2[j] = hb;
                    l2[j] = bf16r(bxr[oo][j] - bf16f(hb));
                }
                Bh[(bu >> 4) * 64 + (bu & 15) + 16 * (bop + 2 * oo)] = h2;
                Bl[(bu >> 4) * 64 + (bu & 15) + 16 * (bop + 2 * oo)] = l2;
            }
        }
        __syncthreads();
        if (ks < 15) {  // prefetch next tiles under the MFMA phase
            const int kb = k0 + (ks + 1) * 32;
#pragma unroll
            for (int j = 0; j < 8; ++j)
                axr[j] = cwr[(size_t)(kb + aoct * 8 + j) * BATCH + bq * 64 + ab];
#pragma unroll
            for (int oo = 0; oo < 2; ++oo)
#pragma unroll
                for (int j = 0; j < 8; ++j)
                    bxr[oo][j] = m[(size_t)(kb + (bop + 2 * oo) * 8 + j) * UNITS + bu];
        }
        short8 a_h = Ah[w * 64 + L], a_l = Al[w * 64 + L];
#pragma unroll
        for (int nt = 0; nt < 8; ++nt) {
            short8 b_h = Bh[nt * 64 + L], b_l = Bl[nt * 64 + L];
            acc[nt] = __builtin_amdgcn_mfma_f32_16x16x32_bf16(a_h, b_h, acc[nt], 0, 0, 0);
            acc[nt] = __builtin_amdgcn_mfma_f32_16x16x32_bf16(a_h, b_l, acc[nt], 0, 0, 0);
            acc[nt] = __builtin_amdgcn_mfma_f32_16x16x32_bf16(a_l, b_h, acc[nt], 0, 0, 0);
        }
        __syncthreads();
    }

    const int rb = bq * 64 + w * 16 + (L >> 4) * 4;
    const int u0 = L & 15;
    if (use_part) {
        float* p = dst + (size_t)kc * (BATCH * UNITS);
#pragma unroll
        for (int nt = 0; nt < 8; ++nt)
#pragma unroll
            for (int r = 0; r < 4; ++r)
                p[(rb + r) * UNITS + nt * 16 + u0] = acc[nt][r];
    } else {
#pragma unroll
        for (int nt = 0; nt < 8; ++nt)
#pragma unroll
            for (int r = 0; r < 4; ++r)
                atomicAdd(&dst[(rb + r) * UNITS + nt * 16 + u0], acc[nt][r]);
    }
}

// ------------------------------------------------------------------
// K8: reduce split-K partials -> read
// ------------------------------------------------------------------
__global__ __launch_bounds__(256) void k_reduce(const float* __restrict__ part,
                                                float* __restrict__ out)
{
    int i = blockIdx.x * 256 + threadIdx.x;     // 0 .. BATCH*UNITS
    float s = 0.f;
#pragma unroll
    for (int c = 0; c < 64; ++c) s += part[c * (BATCH * UNITS) + i];
    out[i] = s;
}

// ------------------------------------------------------------------
extern "C" void kernel_launch(void* const* d_in, const int* in_sizes, int n_in,
                              void* d_out, int out_size, void* d_ws, size_t ws_size,
                              hipStream_t stream)
{
    (void)in_sizes; (void)n_in; (void)out_size;
    const float* inp      = (const float*)d_in[0];
    const float* r_tm1    = (const float*)d_in[1];
    const float* m_tm1    = (const float*)d_in[2];
    const float* cwu_tm1  = (const float*)d_in[3];
    const float* cwlu_tm1 = (const float*)d_in[4];
    const float* cwr_tm1  = (const float*)d_in[5];
    // d_in[6] = c_ww_tm1: unused by the reference
    const float* h_tm1    = (const float*)d_in[7];
    const float* c_tm1    = (const float*)d_in[8];
    const float* W        = (const float*)d_in[9];
    const float* RW       = (const float*)d_in[10];
    const float* bias     = (const float*)d_in[11];
    const float* wgp      = (const float*)d_in[12];

    float* out = (float*)d_out;
    char* ws = (char*)d_ws;
    float* hT   = (float*)(ws + WS_HT);
    unsigned long long* colmin = (unsigned long long*)(ws + WS_COLMIN);
    float* minv = (float*)(ws + WS_MINV);
    int* count  = (int*)(ws + WS_COUNT);
    short8* Bhi = (short8*)(ws + WS_BHI);
    short8* Blo = (short8*)(ws + WS_BLO);
    float* part = (float*)(ws + WS_PART);
    const int use_part = (ws_size >= (size_t)WS_PART + PART_BYTES) ? 1 : 0;

    // A operand (swizzled bf16 hi/lo, 8 MB each) lives in the CWLU output
    // region, which is not written until k_wlu (after k_cos consumed it).
    short8* Ahi = (short8*)(out + OFF_CWLU);
    short8* Alo = Ahi + (MEM * UNITS / 8);
    // Raw-h MFMA-B fragments live in the READ output region (128 KB exactly);
    // consumed by k_memory, then overwritten by k_reduce / k_read-atomic.
    short8* B2h = (short8*)(out + OFF_READ);
    short8* B2l = (short8*)(out + OFF_READ + 16384);   // +64 KB

    hipMemsetAsync(colmin, 0xFF, BATCH * sizeof(unsigned long long), stream);
    hipMemsetAsync(count, 0, MEM * sizeof(int), stream);

    k_lstm<<<BATCH / 4, 512, 0, stream>>>(inp, r_tm1, h_tm1, c_tm1, W, RW, bias, out, hT);
    k_hswz<<<16, 256, 0, stream>>>(hT, Bhi, Blo, out + OFF_H, B2h, B2l);
    k_prep_m<<<MEM / 16, 256, 0, stream>>>(m_tm1, Ahi, Alo);
    k_cos_softmax<<<MEM / 32, 256, 0, stream>>>(Ahi, Alo, Bhi, Blo,
                                                cwr_tm1, cwlu_tm1, cwu_tm1, wgp,
                                                out, colmin);
    k_decode<<<1, BATCH, 0, stream>>>(colmin, minv, count);
    k_wlu<<<(MEM * BATCH / 4) / 256, 256, 0, stream>>>(out + OFF_CWU, minv, out + OFF_CWLU);
    k_memory<<<MEM / 128, 256, 0, stream>>>(out + OFF_CWW, B2h, B2l, m_tm1, count,
                                            out + OFF_MEMORY);
    if (!use_part)   // zero AFTER k_memory: B2 frags live in OFF_READ until then
        hipMemsetAsync(out + OFF_READ, 0, BATCH * UNITS * sizeof(float), stream);
    k_read<<<256, 256, 0, stream>>>(out + OFF_CWR, m_tm1,
                                    use_part ? part : (out + OFF_READ), use_part);
    if (use_part)
        k_reduce<<<(BATCH * UNITS) / 256, 256, 0, stream>>>(part, out + OFF_READ);
}

// Round 2
// 436.785 us; speedup vs baseline: 1.1001x; 1.0369x over previous
//
#include <hip/hip_runtime.h>
#include <math.h>

#define MEM 32768
#define UNITS 128
#define BATCH 256
#define IN_DIM 512
#define ZDIM 512      // 4*UNITS
#define CI_DIM 768    // IN_DIM + UNITS(r) + UNITS(h)

// ---- d_out offsets (floats), reference return order ----
#define OFF_READ   0
#define OFF_MEMORY (OFF_READ + BATCH*UNITS)        // 32768
#define OFF_CWU    (OFF_MEMORY + MEM*UNITS)        // 4227072
#define OFF_CWLU   (OFF_CWU + MEM*BATCH)           // 12615680
#define OFF_CWR    (OFF_CWLU + MEM*BATCH)          // 21004288
#define OFF_CWW    (OFF_CWR + MEM*BATCH)           // 29392896
#define OFF_H      (OFF_CWW + MEM*BATCH)           // 37781504
#define OFF_C      (OFF_H + BATCH*UNITS)           // 37814272

// ---- ws offsets (bytes) ----
#define WS_HT     0                                // float[UNITS*BATCH] (scaled h^T)
#define WS_COLMIN (UNITS*BATCH*4)                  // u64[BATCH]          (131072)
#define WS_B2H    (WS_COLMIN + BATCH*8)            // short8 raw-h frags  (133120)
#define WS_B2L    (WS_B2H + 65536)
#define WS_BHI    (WS_B2L + 65536)                 // short8 swizzled hT hi (64 KB)
#define WS_BLO    (WS_BHI + 65536)                 // ends 395264
#define WS_PART   (512*1024)                       // float[64][BATCH][UNITS] split-K partials
#define PART_BYTES (64*BATCH*UNITS*4)              // 8 MB

typedef __attribute__((ext_vector_type(8))) short short8;
typedef __attribute__((ext_vector_type(4))) float f32x4;

__device__ __forceinline__ float sigf(float x) { return 1.0f / (1.0f + __expf(-x)); }
// bf16 round-to-nearest-even from f32 (bits as short)
__device__ __forceinline__ short bf16r(float x) {
    unsigned u = __float_as_uint(x);
    return (short)((u + 0x7fffu + ((u >> 16) & 1u)) >> 16);
}
__device__ __forceinline__ float bf16f(short h) {
    return __uint_as_float(((unsigned)(unsigned short)h) << 16);
}

// ------------------------------------------------------------------
// K1: LSTM cell (4 rows/block), h/c outputs, h-norm, scaled h^T to ws
// ------------------------------------------------------------------
__global__ __launch_bounds__(512) void k_lstm(
    const float* __restrict__ inp, const float* __restrict__ r_tm1,
    const float* __restrict__ h_tm1, const float* __restrict__ c_tm1,
    const float* __restrict__ W, const float* __restrict__ RW,
    const float* __restrict__ bias,
    float* __restrict__ out, float* __restrict__ hT)
{
    __shared__ float ci[4][CI_DIM];
    __shared__ float zl[4][ZDIM];
    __shared__ float part[8];
    const int t = threadIdx.x;
    const int row0 = blockIdx.x * 4;

    for (int i = t; i < 4 * CI_DIM; i += 512) {
        int r = i / CI_DIM, j = i - r * CI_DIM;
        int row = row0 + r;
        float v;
        if (j < IN_DIM)              v = inp[row * IN_DIM + j];
        else if (j < IN_DIM + UNITS) v = r_tm1[row * UNITS + (j - IN_DIM)];
        else                         v = h_tm1[row * UNITS + (j - IN_DIM - UNITS)];
        ci[r][j] = v;
    }
    __syncthreads();

    float b = bias[t];
    float z0 = b, z1 = b, z2 = b, z3 = b;
    for (int k4 = 0; k4 < (IN_DIM + UNITS) / 4; ++k4) {
        float w0 = W[(k4 * 4 + 0) * ZDIM + t];
        float w1 = W[(k4 * 4 + 1) * ZDIM + t];
        float w2 = W[(k4 * 4 + 2) * ZDIM + t];
        float w3 = W[(k4 * 4 + 3) * ZDIM + t];
        float4 a0 = *(const float4*)&ci[0][k4 * 4];
        float4 a1 = *(const float4*)&ci[1][k4 * 4];
        float4 a2 = *(const float4*)&ci[2][k4 * 4];
        float4 a3 = *(const float4*)&ci[3][k4 * 4];
        z0 += a0.x * w0 + a0.y * w1 + a0.z * w2 + a0.w * w3;
        z1 += a1.x * w0 + a1.y * w1 + a1.z * w2 + a1.w * w3;
        z2 += a2.x * w0 + a2.y * w1 + a2.z * w2 + a2.w * w3;
        z3 += a3.x * w0 + a3.y * w1 + a3.z * w2 + a3.w * w3;
    }
    for (int k4 = 0; k4 < UNITS / 4; ++k4) {
        float w0 = RW[(k4 * 4 + 0) * ZDIM + t];
        float w1 = RW[(k4 * 4 + 1) * ZDIM + t];
        float w2 = RW[(k4 * 4 + 2) * ZDIM + t];
        float w3 = RW[(k4 * 4 + 3) * ZDIM + t];
        const int base = IN_DIM + UNITS + k4 * 4;
        float4 a0 = *(const float4*)&ci[0][base];
        float4 a1 = *(const float4*)&ci[1][base];
        float4 a2 = *(const float4*)&ci[2][base];
        float4 a3 = *(const float4*)&ci[3][base];
        z0 += a0.x * w0 + a0.y * w1 + a0.z * w2 + a0.w * w3;
        z1 += a1.x * w0 + a1.y * w1 + a1.z * w2 + a1.w * w3;
        z2 += a2.x * w0 + a2.y * w1 + a2.z * w2 + a2.w * w3;
        z3 += a3.x * w0 + a3.y * w1 + a3.z * w2 + a3.w * w3;
    }
    zl[0][t] = z0; zl[1][t] = z1; zl[2][t] = z2; zl[3][t] = z3;
    __syncthreads();

    const int r = t >> 7, u = t & 127;
    const int row = row0 + r;
    float iv = zl[r][u], fv = zl[r][UNITS + u], gv = zl[r][2 * UNITS + u], ov = zl[r][3 * UNITS + u];
    float ig = sigf(iv), fg = sigf(fv), og = sigf(ov);
    float gt = tanhf(gv);
    float cn = fg * c_tm1[row * UNITS + u] + ig * gt;
    float hn = og * tanhf(cn);
    out[OFF_C + row * UNITS + u] = cn;
    out[OFF_H + row * UNITS + u] = hn;

    float s = hn * hn;
    for (int d = 1; d < 64; d <<= 1) s += __shfl_xor(s, d, 64);
    int wave = t >> 6;
    if ((t & 63) == 0) part[wave] = s;
    __syncthreads();
    float inv = rsqrtf(fmaxf(part[2 * r] + part[2 * r + 1], 1e-12f));
    hT[u * BATCH + row] = hn * inv;
}

// ------------------------------------------------------------------
// K2: swizzle normalized h^T into MFMA-B layout (bf16 hi/lo), and
// (blocks 0..7) swizzle raw h into K-major MFMA-B fragments for k_memory.
// ------------------------------------------------------------------
__global__ __launch_bounds__(256) void k_hswz(
    const float* __restrict__ hT, short8* __restrict__ Bhi, short8* __restrict__ Blo,
    const float* __restrict__ h, short8* __restrict__ B2h, short8* __restrict__ B2l)
{
    const int t = threadIdx.x, bt = blockIdx.x;
    const int s = t >> 6, L = t & 63;
    const int b = bt * 16 + (L & 15);
    const int k0 = s * 32 + (L >> 4) * 8;
    short8 hi, lo;
#pragma unroll
    for (int j = 0; j < 8; ++j) {
        float x = hT[(k0 + j) * BATCH + b];
        short hb = bf16r(x);
        hi[j] = hb;
        lo[j] = bf16r(x - bf16f(hb));
    }
    Bhi[bt * 256 + t] = hi;
    Blo[bt * 256 + t] = lo;

    if (bt < 8) {  // raw-h fragments (K = batch), block bt covers b-rows bt*32..+31
        const int u = t & 127, op = t >> 7;
#pragma unroll
        for (int oo = 0; oo < 2; ++oo) {
            const int oct = op + 2 * oo;
            short8 h2, l2;
#pragma unroll
            for (int j = 0; j < 8; ++j) {
                float x = h[(bt * 32 + oct * 8 + j) * UNITS + u];
                short hb = bf16r(x);
                h2[j] = hb;
                l2[j] = bf16r(x - bf16f(hb));
            }
            B2h[(bt * 8 + (u >> 4)) * 64 + (u & 15) + 16 * oct] = h2;
            B2l[(bt * 8 + (u >> 4)) * 64 + (u & 15) + 16 * oct] = l2;
        }
    }
}

// ------------------------------------------------------------------
// K3 v3: fused m-normalize+frag (was k_prep_m) + cos MFMA + softmax +
// c_wr/c_ww/c_wu + col-min. A frags live in LDS aliased onto cosLS
// (frags are register-loaded before the first cosLS write).
// ------------------------------------------------------------------
__global__ __launch_bounds__(256) void k_cos_softmax(
    const float* __restrict__ m,
    const short8* __restrict__ Bhi, const short8* __restrict__ Blo,
    const float* __restrict__ cwr_tm1, const float* __restrict__ cwlu_tm1,
    const float* __restrict__ cwu_tm1, const float* __restrict__ wgp,
    float* __restrict__ out, unsigned long long* __restrict__ colmin)
{
    __shared__ float cosLS[32 * 260];          // 33280 B; aliased: A frags + norm scratch
    short8* AhL = (short8*)cosLS;              // 512 entries (8 KB)
    short8* AlL = AhL + 512;                   // 8 KB
    float*  pnorm = cosLS + 4096;              // 544 floats
    const int t = threadIdx.x;
    const int w = t >> 6, L = t & 63;
    const int m0 = blockIdx.x * 32;

    // ---- phase 0: load 32 m-rows, row-normalize, build A frags in LDS ----
    // role (per half hf): row = m0 + hf*16 + (L&15), k0 = w*32 + (L>>4)*8
    float x[2][8];
    const int k0 = w * 32 + (L >> 4) * 8;
#pragma unroll
    for (int hf = 0; hf < 2; ++hf) {
        const int row = m0 + hf * 16 + (L & 15);
        float4 v0 = *(const float4*)&m[row * UNITS + k0];
        float4 v1 = *(const float4*)&m[row * UNITS + k0 + 4];
        x[hf][0] = v0.x; x[hf][1] = v0.y; x[hf][2] = v0.z; x[hf][3] = v0.w;
        x[hf][4] = v1.x; x[hf][5] = v1.y; x[hf][6] = v1.z; x[hf][7] = v1.w;
        float ss = 0.f;
#pragma unroll
        for (int j = 0; j < 8; ++j) ss += x[hf][j] * x[hf][j];
        pnorm[(hf * 16 + (L & 15)) * 17 + w * 4 + (L >> 4)] = ss;
    }
    __syncthreads();
#pragma unroll
    for (int hf = 0; hf < 2; ++hf) {
        const int rl = hf * 16 + (L & 15);
        float tot = 0.f;
#pragma unroll
        for (int i = 0; i < 16; ++i) tot += pnorm[rl * 17 + i];
        float inv = rsqrtf(fmaxf(tot, 1e-12f));
        short8 hi, lo;
#pragma unroll
        for (int j = 0; j < 8; ++j) {
            float xv = x[hf][j] * inv;
            short hb = bf16r(xv);
            hi[j] = hb;
            lo[j] = bf16r(xv - bf16f(hb));
        }
        AhL[(hf * 4 + w) * 64 + L] = hi;
        AlL[(hf * 4 + w) * 64 + L] = lo;
    }
    __syncthreads();

    // ---- load A frags to registers, then free the aliased LDS ----
    const int half = w >> 1, bh = w & 1;
    short8 ah[4], al[4];
#pragma unroll
    for (int s = 0; s < 4; ++s) {
        ah[s] = AhL[(half * 4 + s) * 64 + L];
        al[s] = AlL[(half * 4 + s) * 64 + L];
    }
    __syncthreads();   // all frag reads done before cosLS writes below

    const int rbase = half * 16 + (L >> 4) * 4;
#pragma unroll
    for (int i = 0; i < 8; ++i) {
        const int bt = bh * 8 + i;
        f32x4 acc = {0.f, 0.f, 0.f, 0.f};
#pragma unroll
        for (int s = 0; s < 4; ++s) {
            short8 bhv = Bhi[(bt * 4 + s) * 64 + L];
            short8 blv = Blo[(bt * 4 + s) * 64 + L];
            acc = __builtin_amdgcn_mfma_f32_16x16x32_bf16(ah[s], bhv, acc, 0, 0, 0);
            acc = __builtin_amdgcn_mfma_f32_16x16x32_bf16(ah[s], blv, acc, 0, 0, 0);
            acc = __builtin_amdgcn_mfma_f32_16x16x32_bf16(al[s], bhv, acc, 0, 0, 0);
        }
        const int col = bt * 16 + (L & 15);
#pragma unroll
        for (int r = 0; r < 4; ++r) cosLS[(rbase + r) * 260 + col] = acc[r];
    }
    __syncthreads();

    // ---- phase 2: per-row softmax + ew outputs; wave w owns rows w*8..w*8+7
    const float wg = sigf(wgp[0]);
    const float wgc = 1.0f - wg;
    unsigned long long mk0 = ~0ULL, mk1 = ~0ULL, mk2 = ~0ULL, mk3 = ~0ULL;

#pragma unroll
    for (int i = 0; i < 8; ++i) {
        int ml = w * 8 + i;
        int row = m0 + ml;
        float4 v = *(const float4*)&cosLS[ml * 260 + L * 4];
        float mx = fmaxf(fmaxf(v.x, v.y), fmaxf(v.z, v.w));
        for (int d = 1; d < 64; d <<= 1) mx = fmaxf(mx, __shfl_xor(mx, d, 64));
        float4 e;
        e.x = __expf(v.x - mx); e.y = __expf(v.y - mx);
        e.z = __expf(v.z - mx); e.w = __expf(v.w - mx);
        float s = e.x + e.y + e.z + e.w;
        for (int d = 1; d < 64; d <<= 1) s += __shfl_xor(s, d, 64);
        float is = 1.0f / s;
        float4 wr; wr.x = e.x * is; wr.y = e.y * is; wr.z = e.z * is; wr.w = e.w * is;
        *(float4*)&out[OFF_CWR + row * BATCH + L * 4] = wr;

        float4 pr = *(const float4*)&cwr_tm1[row * BATCH + L * 4];
        float4 pl = *(const float4*)&cwlu_tm1[row * BATCH + L * 4];
        float4 ww;
        ww.x = wg * pr.x + wgc + pl.x; ww.y = wg * pr.y + wgc + pl.y;
        ww.z = wg * pr.z + wgc + pl.z; ww.w = wg * pr.w + wgc + pl.w;
        *(float4*)&out[OFF_CWW + row * BATCH + L * 4] = ww;

        float4 pu = *(const float4*)&cwu_tm1[row * BATCH + L * 4];
        float4 wu;
        wu.x = 0.95f * pu.x + wr.x + ww.x; wu.y = 0.95f * pu.y + wr.y + ww.y;
        wu.z = 0.95f * pu.z + wr.z + ww.z; wu.w = 0.95f * pu.w + wr.w + ww.w;
        *(float4*)&out[OFF_CWU + row * BATCH + L * 4] = wu;

        unsigned idxc = (unsigned)(MEM - 1 - row);
        unsigned long long k;
        k = ((unsigned long long)__float_as_uint(wu.x) << 32) | idxc; if (k < mk0) mk0 = k;
        k = ((unsigned long long)__float_as_uint(wu.y) << 32) | idxc; if (k < mk1) mk1 = k;
        k = ((unsigned long long)__float_as_uint(wu.z) << 32) | idxc; if (k < mk2) mk2 = k;
        k = ((unsigned long long)__float_as_uint(wu.w) << 32) | idxc; if (k < mk3) mk3 = k;
    }
    __syncthreads();
    unsigned long long* wmin = (unsigned long long*)cosLS;
    wmin[w * BATCH + L * 4 + 0] = mk0;
    wmin[w * BATCH + L * 4 + 1] = mk1;
    wmin[w * BATCH + L * 4 + 2] = mk2;
    wmin[w * BATCH + L * 4 + 3] = mk3;
    __syncthreads();
    {
        unsigned long long a = wmin[t];
        unsigned long long b2 = wmin[BATCH + t];
        unsigned long long c2 = wmin[2 * BATCH + t];
        unsigned long long d2 = wmin[3 * BATCH + t];
        unsigned long long k = a < b2 ? a : b2;
        if (c2 < k) k = c2;
        if (d2 < k) k = d2;
        if (k < colmin[t]) atomicMin(&colmin[t], k);
    }
}

// ------------------------------------------------------------------
// K5 v2: c_wlu = (c_wu <= minv[b]); minv decoded from colmin in LDS.
// 4 consecutive float4s per thread.
// ------------------------------------------------------------------
__global__ __launch_bounds__(256) void k_wlu(const float* __restrict__ cwu,
                                             const unsigned long long* __restrict__ colmin,
                                             float* __restrict__ wlu)
{
    __shared__ float mvs[256];
    const int t = threadIdx.x;
    mvs[t] = __uint_as_float((unsigned)(colmin[t] >> 32));
    __syncthreads();
    const int i0 = (blockIdx.x * 256 + t) * 4;   // float4 index
#pragma unroll
    for (int j = 0; j < 4; ++j) {
        const int i = i0 + j;
        float4 v = *(const float4*)&cwu[(size_t)i * 4];
        float4 mv = *(const float4*)&mvs[(i & 63) * 4];
        float4 r;
        r.x = (v.x <= mv.x) ? 1.0f : 0.0f;
        r.y = (v.y <= mv.y) ? 1.0f : 0.0f;
        r.z = (v.z <= mv.z) ? 1.0f : 0.0f;
        r.w = (v.w <= mv.w) ? 1.0f : 0.0f;
        *(float4*)&wlu[(size_t)i * 4] = r;
    }
}

// ------------------------------------------------------------------
// K7 v3: read = c_wr^T @ m via MFMA bf16 hi/lo split, split-K.
// ------------------------------------------------------------------
__global__ __launch_bounds__(256) void k_read(
    const float* __restrict__ cwr, const float* __restrict__ m,
    float* __restrict__ dst, int use_part)
{
    __shared__ short8 Ah[4 * 64], Al[4 * 64];
    __shared__ short8 Bh[8 * 64], Bl[8 * 64];
    const int t = threadIdx.x;
    const int w = t >> 6, L = t & 63;
    const int kc = blockIdx.x >> 2;
    const int bq = blockIdx.x & 3;
    const int k0 = kc * 512;

    const int ab = t & 63;           // b within quarter (A staging role)
    const int aoct = t >> 6;         // 0..3
    const int bu = t & 127;          // u (B staging role)
    const int bop = t >> 7;          // 0..1

    f32x4 zero = {0.f, 0.f, 0.f, 0.f};
    f32x4 acc[8];
#pragma unroll
    for (int i = 0; i < 8; ++i) acc[i] = zero;

    float axr[8];
    float bxr[2][8];
#pragma unroll
    for (int j = 0; j < 8; ++j)
        axr[j] = cwr[(size_t)(k0 + aoct * 8 + j) * BATCH + bq * 64 + ab];
#pragma unroll
    for (int oo = 0; oo < 2; ++oo)
#pragma unroll
        for (int j = 0; j < 8; ++j)
            bxr[oo][j] = m[(size_t)(k0 + (bop + 2 * oo) * 8 + j) * UNITS + bu];

    for (int ks = 0; ks < 16; ++ks) {
        {   // convert & store fragments
            short8 hi, lo;
#pragma unroll
            for (int j = 0; j < 8; ++j) {
                short hb = bf16r(axr[j]);
                hi[j] = hb;
                lo[j] = bf16r(axr[j] - bf16f(hb));
            }
            Ah[(ab >> 4) * 64 + (ab & 15) + 16 * aoct] = hi;
            Al[(ab >> 4) * 64 + (ab & 15) + 16 * aoct] = lo;
#pragma unroll
            for (int oo = 0; oo < 2; ++oo) {
                short8 h2, l2;
#pragma unroll
                for (int j = 0; j < 8; ++j) {
                    short hb = bf16r(bxr[oo][j]);
                    h2[j] = hb;
                    l2[j] = bf16r(bxr[oo][j] - bf16f(hb));
                }
                Bh[(bu >> 4) * 64 + (bu & 15) + 16 * (bop + 2 * oo)] = h2;
                Bl[(bu >> 4) * 64 + (bu & 15) + 16 * (bop + 2 * oo)] = l2;
            }
        }
        __syncthreads();
        if (ks < 15) {  // prefetch next tiles under the MFMA phase
            const int kb = k0 + (ks + 1) * 32;
#pragma unroll
            for (int j = 0; j < 8; ++j)
                axr[j] = cwr[(size_t)(kb + aoct * 8 + j) * BATCH + bq * 64 + ab];
#pragma unroll
            for (int oo = 0; oo < 2; ++oo)
#pragma unroll
                for (int j = 0; j < 8; ++j)
                    bxr[oo][j] = m[(size_t)(kb + (bop + 2 * oo) * 8 + j) * UNITS + bu];
        }
        short8 a_h = Ah[w * 64 + L], a_l = Al[w * 64 + L];
#pragma unroll
        for (int nt = 0; nt < 8; ++nt) {
            short8 b_h = Bh[nt * 64 + L], b_l = Bl[nt * 64 + L];
            acc[nt] = __builtin_amdgcn_mfma_f32_16x16x32_bf16(a_h, b_h, acc[nt], 0, 0, 0);
            acc[nt] = __builtin_amdgcn_mfma_f32_16x16x32_bf16(a_h, b_l, acc[nt], 0, 0, 0);
            acc[nt] = __builtin_amdgcn_mfma_f32_16x16x32_bf16(a_l, b_h, acc[nt], 0, 0, 0);
        }
        __syncthreads();
    }

    const int rb = bq * 64 + w * 16 + (L >> 4) * 4;
    const int u0 = L & 15;
    if (use_part) {
        float* p = dst + (size_t)kc * (BATCH * UNITS);
#pragma unroll
        for (int nt = 0; nt < 8; ++nt)
#pragma unroll
            for (int r = 0; r < 4; ++r)
                p[(rb + r) * UNITS + nt * 16 + u0] = acc[nt][r];
    } else {
#pragma unroll
        for (int nt = 0; nt < 8; ++nt)
#pragma unroll
            for (int r = 0; r < 4; ++r)
                atomicAdd(&dst[(rb + r) * UNITS + nt * 16 + u0], acc[nt][r]);
    }
}

// ------------------------------------------------------------------
// K6 v4: memory = c_ww @ h + (BATCH - count)*m, MFMA bf16 hi/lo split.
// Fused: per-block argmin counts decoded from colmin (LDS), and the
// split-K 'read' reduction (block owns slice [bid*128, +128)).
// ------------------------------------------------------------------
__global__ __launch_bounds__(256) void k_memory(
    const float* __restrict__ cww, const short8* __restrict__ B2h,
    const short8* __restrict__ B2l, const float* __restrict__ m,
    const unsigned long long* __restrict__ colmin,
    const float* __restrict__ part, float* __restrict__ mem_out,
    float* __restrict__ read_out, int use_part)
{
    __shared__ short8 Ah[8 * 64], Al[8 * 64];
    __shared__ int cnt[128];
    const int t = threadIdx.x;
    const int w = t >> 6, L = t & 63;
    const int m0 = blockIdx.x * 128;
    const int mr = t & 127;          // m-row within block (A staging role)
    const int op = t >> 7;           // octet pair selector

    if (t < 128) cnt[t] = 0;
    __syncthreads();
    {   // count argmins falling in this block's row range
        unsigned long long k = colmin[t];
        int idx = MEM - 1 - (int)(unsigned)(k & 0xffffffffu);
        unsigned rel = (unsigned)(idx - m0);
        if (rel < 128u) atomicAdd(&cnt[rel], 1);
    }
    if (use_part && t < 128) {   // fused split-K reduce for 'read'
        const int slice = blockIdx.x * 128;
        float s = 0.f;
#pragma unroll
        for (int c = 0; c < 64; ++c) s += part[c * (BATCH * UNITS) + slice + t];
        read_out[slice + t] = s;
    }

    f32x4 zero = {0.f, 0.f, 0.f, 0.f};
    f32x4 acc[2][8];
#pragma unroll
    for (int mi = 0; mi < 2; ++mi)
#pragma unroll
        for (int nt = 0; nt < 8; ++nt) acc[mi][nt] = zero;

    // prefetch A tile for ks=0: cww[m0+mr][oct*8 .. +8]
    float ax[2][8];
#pragma unroll
    for (int oo = 0; oo < 2; ++oo) {
        const float* src = &cww[(size_t)(m0 + mr) * BATCH + (op + 2 * oo) * 8];
        float4 v0 = *(const float4*)src;
        float4 v1 = *(const float4*)(src + 4);
        ax[oo][0] = v0.x; ax[oo][1] = v0.y; ax[oo][2] = v0.z; ax[oo][3] = v0.w;
        ax[oo][4] = v1.x; ax[oo][5] = v1.y; ax[oo][6] = v1.z; ax[oo][7] = v1.w;
    }

    for (int ks = 0; ks < 8; ++ks) {
        // convert & store A fragments
#pragma unroll
        for (int oo = 0; oo < 2; ++oo) {
            const int oct = op + 2 * oo;
            short8 hi, lo;
#pragma unroll
            for (int j = 0; j < 8; ++j) {
                short hb = bf16r(ax[oo][j]);
                hi[j] = hb;
                lo[j] = bf16r(ax[oo][j] - bf16f(hb));
            }
            Ah[(mr >> 4) * 64 + (mr & 15) + 16 * oct] = hi;
            Al[(mr >> 4) * 64 + (mr & 15) + 16 * oct] = lo;
        }
        __syncthreads();
        if (ks < 7) {   // prefetch next A tile under the MFMA phase
#pragma unroll
            for (int oo = 0; oo < 2; ++oo) {
                const float* src = &cww[(size_t)(m0 + mr) * BATCH + (ks + 1) * 32 + (op + 2 * oo) * 8];
                float4 v0 = *(const float4*)src;
                float4 v1 = *(const float4*)(src + 4);
                ax[oo][0] = v0.x; ax[oo][1] = v0.y; ax[oo][2] = v0.z; ax[oo][3] = v0.w;
                ax[oo][4] = v1.x; ax[oo][5] = v1.y; ax[oo][6] = v1.z; ax[oo][7] = v1.w;
            }
        }
        short8 a_h0 = Ah[(2 * w) * 64 + L],     a_l0 = Al[(2 * w) * 64 + L];
        short8 a_h1 = Ah[(2 * w + 1) * 64 + L], a_l1 = Al[(2 * w + 1) * 64 + L];
#pragma unroll
        for (int nt = 0; nt < 8; ++nt) {
            short8 b_h = B2h[(ks * 8 + nt) * 64 + L];
            short8 b_l = B2l[(ks * 8 + nt) * 64 + L];
            acc[0][nt] = __builtin_amdgcn_mfma_f32_16x16x32_bf16(a_h0, b_h, acc[0][nt], 0, 0, 0);
            acc[0][nt] = __builtin_amdgcn_mfma_f32_16x16x32_bf16(a_h0, b_l, acc[0][nt], 0, 0, 0);
            acc[0][nt] = __builtin_amdgcn_mfma_f32_16x16x32_bf16(a_l0, b_h, acc[0][nt], 0, 0, 0);
            acc[1][nt] = __builtin_amdgcn_mfma_f32_16x16x32_bf16(a_h1, b_h, acc[1][nt], 0, 0, 0);
            acc[1][nt] = __builtin_amdgcn_mfma_f32_16x16x32_bf16(a_h1, b_l, acc[1][nt], 0, 0, 0);
            acc[1][nt] = __builtin_amdgcn_mfma_f32_16x16x32_bf16(a_l1, b_h, acc[1][nt], 0, 0, 0);
        }
        __syncthreads();
    }

    // epilogue: C row = mt*16 + (L>>4)*4 + r, col = nt*16 + (L&15)
#pragma unroll
    for (int mi = 0; mi < 2; ++mi) {
#pragma unroll
        for (int r = 0; r < 4; ++r) {
            const int rl = (2 * w + mi) * 16 + (L >> 4) * 4 + r;
            const int row = m0 + rl;
            const float sc = (float)(BATCH - cnt[rl]);
#pragma unroll
            for (int nt = 0; nt < 8; ++nt) {
                const int u = nt * 16 + (L & 15);
                mem_out[row * UNITS + u] = acc[mi][nt][r] + sc * m[row * UNITS + u];
            }
        }
    }
}

// ------------------------------------------------------------------
extern "C" void kernel_launch(void* const* d_in, const int* in_sizes, int n_in,
                              void* d_out, int out_size, void* d_ws, size_t ws_size,
                              hipStream_t stream)
{
    (void)in_sizes; (void)n_in; (void)out_size;
    const float* inp      = (const float*)d_in[0];
    const float* r_tm1    = (const float*)d_in[1];
    const float* m_tm1    = (const float*)d_in[2];
    const float* cwu_tm1  = (const float*)d_in[3];
    const float* cwlu_tm1 = (const float*)d_in[4];
    const float* cwr_tm1  = (const float*)d_in[5];
    // d_in[6] = c_ww_tm1: unused by the reference
    const float* h_tm1    = (const float*)d_in[7];
    const float* c_tm1    = (const float*)d_in[8];
    const float* W        = (const float*)d_in[9];
    const float* RW       = (const float*)d_in[10];
    const float* bias     = (const float*)d_in[11];
    const float* wgp      = (const float*)d_in[12];

    float* out = (float*)d_out;
    char* ws = (char*)d_ws;
    float* hT   = (float*)(ws + WS_HT);
    unsigned long long* colmin = (unsigned long long*)(ws + WS_COLMIN);
    short8* B2h = (short8*)(ws + WS_B2H);
    short8* B2l = (short8*)(ws + WS_B2L);
    short8* Bhi = (short8*)(ws + WS_BHI);
    short8* Blo = (short8*)(ws + WS_BLO);
    float* part = (float*)(ws + WS_PART);
    const int use_part = (ws_size >= (size_t)WS_PART + PART_BYTES) ? 1 : 0;

    hipMemsetAsync(colmin, 0xFF, BATCH * sizeof(unsigned long long), stream);
    if (!use_part)
        hipMemsetAsync(out + OFF_READ, 0, BATCH * UNITS * sizeof(float), stream);

    k_lstm<<<BATCH / 4, 512, 0, stream>>>(inp, r_tm1, h_tm1, c_tm1, W, RW, bias, out, hT);
    k_hswz<<<16, 256, 0, stream>>>(hT, Bhi, Blo, out + OFF_H, B2h, B2l);
    k_cos_softmax<<<MEM / 32, 256, 0, stream>>>(m_tm1, Bhi, Blo,
                                                cwr_tm1, cwlu_tm1, cwu_tm1, wgp,
                                                out, colmin);
    k_wlu<<<MEM * BATCH / 4096, 256, 0, stream>>>(out + OFF_CWU, colmin, out + OFF_CWLU);
    k_read<<<256, 256, 0, stream>>>(out + OFF_CWR, m_tm1,
                                    use_part ? part : (out + OFF_READ), use_part);
    k_memory<<<MEM / 128, 256, 0, stream>>>(out + OFF_CWW, B2h, B2l, m_tm1, colmin,
                                            part, out + OFF_MEMORY,
                                            out + OFF_READ, use_part);
}